// Round 13
// baseline (271.140 us; speedup 1.0000x reference)
//
#include <hip/hip_runtime.h>
#include <cstdint>

#define N_TOK 4096
#define DMODEL 1024
#define DFFC 2048
#define NEXP 8
#define NR (N_TOK*2)      /* 8192 expanded rows (top-2) */

typedef unsigned short ushort_t;
typedef __attribute__((ext_vector_type(8))) short short8v;   // 8 bf16
typedef __attribute__((ext_vector_type(4))) float float4v;   // MFMA C/D

__device__ __forceinline__ ushort_t f2bf(float f){
  union { float f; unsigned u; } v; v.f = f;
  unsigned r = v.u + 0x7fffu + ((v.u >> 16) & 1u);
  return (ushort_t)(r >> 16);
}

__device__ __forceinline__ void gl_lds16(const void* g, void* l){
  __builtin_amdgcn_global_load_lds((const __attribute__((address_space(1))) char*)g,
                                   (__attribute__((address_space(3))) char*)l, 16, 0, 0);
}

// swizzled fragment element-offset inside a [rows][64] bf16 tile (128B rows, 8 slots of 16B)
__device__ __forceinline__ int frag_off(int row, int slotc){
  return row*64 + ((slotc ^ (row & 7)))*8;
}

__device__ __forceinline__ void fma4(float4& a, float s, float4 q){
  a.x += s*q.x; a.y += s*q.y; a.z += s*q.z; a.w += s*q.w;
}

// ------- router (atomic-free): logits fp32 (exact), top-2 -> sel/wslot; emits bf16 x --------
// 256 thr = 4 waves, one token per wave.  [measured ~20 us]
__global__ __launch_bounds__(256) void router_k(const float* __restrict__ x,
                         const float* __restrict__ Wg, const float* __restrict__ bg,
                         float* __restrict__ logits, int* __restrict__ sel,
                         float* __restrict__ wslot, ushort_t* __restrict__ Xbf){
  int wid = threadIdx.x >> 6;
  int l   = threadIdx.x & 63;
  int t = blockIdx.x*4 + wid;
  const float4* xr = (const float4*)(x + (size_t)t * DMODEL);
  ushort_t* xb = Xbf + (size_t)t * DMODEL;
  float4 acc0 = {0,0,0,0}, acc1 = {0,0,0,0};
  #pragma unroll
  for (int it=0; it<4; ++it){
    int i4 = it*64 + l;
    float4 v = xr[i4];
    const float4* wr4 = (const float4*)(Wg + (size_t)i4*32);
    fma4(acc0, v.x, wr4[0]); fma4(acc1, v.x, wr4[1]);
    fma4(acc0, v.y, wr4[2]); fma4(acc1, v.y, wr4[3]);
    fma4(acc0, v.z, wr4[4]); fma4(acc1, v.z, wr4[5]);
    fma4(acc0, v.w, wr4[6]); fma4(acc1, v.w, wr4[7]);
    ushort4 o; o.x=f2bf(v.x); o.y=f2bf(v.y); o.z=f2bf(v.z); o.w=f2bf(v.w);
    *(ushort4*)(xb + 4*i4) = o;
  }
  float lg[NEXP] = {acc0.x, acc0.y, acc0.z, acc0.w, acc1.x, acc1.y, acc1.z, acc1.w};
  #pragma unroll
  for (int e=0;e<NEXP;e++){
    float v = lg[e];
    #pragma unroll
    for (int s=32;s>0;s>>=1) v += __shfl_xor(v,s);
    lg[e] = v;
  }
  if (l==0){
    float m=-1e30f;
    #pragma unroll
    for (int e=0;e<NEXP;e++){ lg[e]+=bg[e]; m = fmaxf(m,lg[e]); }
    float p[NEXP];
    #pragma unroll
    for (int e=0;e<NEXP;e++) p[e]=__expf(lg[e]-m);
    int e0=0;
    #pragma unroll
    for (int e=1;e<NEXP;e++) if (p[e]>p[e0]) e0=e;      // strict > : lower idx wins ties
    int e1=(e0==0)?1:0;
    #pragma unroll
    for (int e=0;e<NEXP;e++) if (e!=e0 && p[e]>p[e1]) e1=e;
    float ps=p[e0]+p[e1];
    float4* lgo = (float4*)(logits + (size_t)t*NEXP);
    lgo[0] = make_float4(lg[0],lg[1],lg[2],lg[3]);
    lgo[1] = make_float4(lg[4],lg[5],lg[6],lg[7]);
    sel[t] = e0 | (e1<<8);
    wslot[t*2+0]=p[e0]/ps; wslot[t*2+1]=p[e1]/ps;
  }
}

// ------- build_k: deterministic per-expert compaction, zero atomics (8 blocks) ---------------
__global__ __launch_bounds__(256) void build_k(const int* __restrict__ sel,
                                               int* __restrict__ elist, int* __restrict__ cnt){
  int e = blockIdx.x;
  int tid = threadIdx.x;
  int w = tid>>6, l = tid&63;
  __shared__ int wtot[4];
  __shared__ int runbase;
  if (tid==0) runbase = 0;
  __syncthreads();
  unsigned long long lt = (1ULL << l) - 1ULL;
  for (int c=0;c<N_TOK/256;c++){
    int t = c*256 + tid;
    int s = sel[t];
    bool f0 = (s & 255) == e;
    bool f1 = ((s>>8) & 255) == e;
    unsigned long long m0 = __ballot(f0);
    unsigned long long m1 = __ballot(f1);
    int myless = __popcll(m0 & lt) + __popcll(m1 & lt);
    if (l==0) wtot[w] = __popcll(m0) + __popcll(m1);
    __syncthreads();
    int pre = 0, tot = 0;
    #pragma unroll
    for (int j=0;j<4;j++){ if (j<w) pre += wtot[j]; tot += wtot[j]; }
    int base = runbase + pre + myless;
    if (f0) elist[e*N_TOK + base] = 2*t;
    if (f1) elist[e*N_TOK + base + (f0?1:0)] = 2*t + 1;
    __syncthreads();
    if (tid==0) runbase += tot;
    __syncthreads();
  }
  if (tid==0) cnt[e] = runbase;
}

__global__ void scan_k(const int* __restrict__ cnt, int* __restrict__ offs){
  if (threadIdx.x==0 && blockIdx.x==0){
    int s=0;
    for (int e=0;e<NEXP;e++){ offs[e]=s; s+=cnt[e]; }
    offs[NEXP]=s;
  }
}

// ------------- weight transpose + fp32->bf16, grid-stride, exact tile decode ----------------
// 2048 blocks (8/CU, full occupancy), e = id&7 XCD pin, 6 tiles/block, zero dead blocks.
// Per expert 1536 tiles: [0,512)=Ww, [512,1024)=Wv, [1024,1536)=Wo.
// Bcat[e] is [4096 cols][1024 k], col = (f>>4)*32 + (is_v?16:0) + (f&15).
__global__ __launch_bounds__(256) void transpose_k(const float* __restrict__ Ww,
                            const float* __restrict__ Wv, const float* __restrict__ Wo,
                            ushort_t* __restrict__ Bcat, ushort_t* __restrict__ WoT){
  int b = blockIdx.x;
  int e    = b & 7;                 // XCD pin: expert e -> XCD e
  int slot = b >> 3;                // 0..255
  int tid = threadIdx.x;
  int g = tid >> 4;                 // k-quad 0..15
  int c = tid & 15;                 // f-quad 0..15 (consecutive lanes walk f: coalesced loads)
  #pragma unroll
  for (int i=0; i<6; ++i){
    int tt = slot*6 + i;            // 0..1535
    const float* src; int F; int fx, ky; int m;
    if (tt < 1024){
      m = tt >> 9;                  // 0 or 1
      int r = tt & 511;
      src = (m ? Wv : Ww) + (size_t)e*DMODEL*DFFC;
      F = DFFC; fx = r & 31; ky = r >> 5;      // 32 f-tiles x 16 k-tiles
    } else {
      m = 2;
      int r = tt - 1024;            // 0..511
      src = Wo + (size_t)e*DFFC*DMODEL;
      F = DMODEL; fx = r & 15; ky = r >> 4;    // 16 f-tiles x 32 k-tiles
    }
    int kk = ky*64 + 4*g;
    int ff = fx*64 + 4*c;
    float4 v0 = *(const float4*)&src[(size_t)(kk+0)*F + ff];
    float4 v1 = *(const float4*)&src[(size_t)(kk+1)*F + ff];
    float4 v2 = *(const float4*)&src[(size_t)(kk+2)*F + ff];
    float4 v3 = *(const float4*)&src[(size_t)(kk+3)*F + ff];
    ushort4 o[4];
    o[0].x=f2bf(v0.x); o[0].y=f2bf(v1.x); o[0].z=f2bf(v2.x); o[0].w=f2bf(v3.x);
    o[1].x=f2bf(v0.y); o[1].y=f2bf(v1.y); o[1].z=f2bf(v2.y); o[1].w=f2bf(v3.y);
    o[2].x=f2bf(v0.z); o[2].y=f2bf(v1.z); o[2].z=f2bf(v2.z); o[2].w=f2bf(v3.z);
    o[3].x=f2bf(v0.w); o[3].y=f2bf(v1.w); o[3].z=f2bf(v2.w); o[3].w=f2bf(v3.w);
    if (m < 2){
      #pragma unroll
      for (int q=0;q<4;q++){
        int f = ff + q;
        int cc = (f>>4)*32 + m*16 + (f&15);
        *(ushort4*)&Bcat[((size_t)e*4096 + cc)*DMODEL + kk] = o[q];
      }
    } else {
      #pragma unroll
      for (int q=0;q<4;q++){
        int f = ff + q;
        *(ushort4*)&WoT[(size_t)e*DMODEL*DFFC + (size_t)f*DFFC + kk] = o[q];
      }
    }
  }
}

// ---- stage helper (256 thr): [128 rows][64 k] tile, 4 gl_lds/thread, inverse-swizzled src ---
__device__ __forceinline__ void stage256(const ushort_t* __restrict__ base, int ldk,
                                         ushort_t* buf, int w, int l){
  int sw = ((l&7) ^ (l>>3))*8;
  #pragma unroll
  for (int j=0;j<4;j++){
    int row = j*32 + w*8 + (l>>3);
    gl_lds16(base + (size_t)row*ldk + sw, &buf[(j*256 + w*64)*8]);
  }
}

// -------- GEMM1: 128x128 m97-style, A indirect via elist, B = interleaved Bcat ---------------
// 4 waves (2x2), single-buffered 32 KB LDS, 4 blocks/CU, expert e -> XCD e.
// Supertiled dispatch: j_ = fs*128 + mt*4 + ftSub  (ft groups of 4 inner, mt next, fs outer)
__global__ __launch_bounds__(256,4) void gemm1_k(const ushort_t* __restrict__ Xbf,
    const int* __restrict__ elist,
    const ushort_t* __restrict__ Bcat,
    const float* __restrict__ bw, const float* __restrict__ bv,
    const int* __restrict__ cnt, const int* __restrict__ offs,
    ushort_t* __restrict__ H){
  __shared__ ushort_t As[128*64];
  __shared__ ushort_t Bs[128*64];
  int id = blockIdx.x;
  int e  = id & 7;                  // XCD pin
  int j_ = id >> 3;                 // 0..1023
  int fs = j_ >> 7;                 // 0..7
  int mt = (j_ >> 2) & 31;          // 0..31
  int ft = fs*4 + (j_ & 3);         // 0..31
  int cnte = cnt[e];
  if (mt*128 >= cnte) return;
  int row0 = offs[e] + mt*128;
  const ushort_t* Bg = Bcat + ((size_t)e*4096 + ft*128)*DMODEL;
  int tid = threadIdx.x;
  int w = tid>>6, l = tid&63;
  int wr = w>>1, wc = w&1;          // wave: rows [wr*64,+64), cols [wc*64,+64)
  int sw = ((l&7) ^ (l>>3))*8;      // inverse-swizzled k-slot (A staging)

  // A indirection: token row per staged LDS row (clamped to valid range)
  int aTok[4];
  #pragma unroll
  for (int j=0;j<4;j++){
    int li = mt*128 + j*32 + w*8 + (l>>3);
    if (li >= cnte) li = cnte-1;
    aTok[j] = elist[e*N_TOK + li] >> 1;
  }

  int aOff[4][2], bOff[4][2];
  #pragma unroll
  for (int m=0;m<4;m++)
    #pragma unroll
    for (int ks=0;ks<2;ks++)
      aOff[m][ks] = frag_off(wr*64 + m*16 + (l&15), ks*4 + (l>>4));
  #pragma unroll
  for (int n=0;n<4;n++)
    #pragma unroll
    for (int ks=0;ks<2;ks++)
      bOff[n][ks] = frag_off(wc*64 + n*16 + (l&15), ks*4 + (l>>4));

  float4v acc[4][4];
  #pragma unroll
  for (int m=0;m<4;m++)
    #pragma unroll
    for (int n=0;n<4;n++) acc[m][n]=(float4v){0,0,0,0};

  const int KT = DMODEL/64;   // 16
  for (int kt=0; kt<KT; ++kt){
    #pragma unroll
    for (int j=0;j<4;j++)
      gl_lds16(Xbf + (size_t)aTok[j]*DMODEL + kt*64 + sw, &As[j*2048 + w*512]);
    stage256(Bg + kt*64, DMODEL, Bs, w, l);
    __syncthreads();
    #pragma unroll
    for (int ks=0; ks<2; ++ks){
      short8v a_[4], b_[4];
      #pragma unroll
      for (int m=0;m<4;m++) a_[m] = *(const short8v*)&As[aOff[m][ks]];
      #pragma unroll
      for (int n=0;n<4;n++) b_[n] = *(const short8v*)&Bs[bOff[n][ks]];
      #pragma unroll
      for (int n=0;n<4;n++)
        #pragma unroll
        for (int m=0;m<4;m++)
          acc[m][n] = __builtin_amdgcn_mfma_f32_16x16x32_bf16(a_[m], b_[n], acc[m][n], 0,0,0);
    }
    __syncthreads();
  }

  int rows_valid = cnte - mt*128; if (rows_valid>128) rows_valid=128;
  #pragma unroll
  for (int m=0;m<4;m++){
    #pragma unroll
    for (int r=0;r<4;r++){
      int row_local = wr*64 + m*16 + (l>>4)*4 + r;
      if (row_local < rows_valid){
        size_t hbase = (size_t)(row0 + row_local)*DFFC;
        #pragma unroll
        for (int np=0;np<2;np++){
          int f = ft*64 + wc*32 + np*16 + (l&15);
          float wx = acc[m][2*np+0][r] + bw[e*DFFC + f];
          float vx = acc[m][2*np+1][r] + bv[e*DFFC + f];
          float h = (wx / (1.f + __expf(-wx))) * vx;
          H[hbase + f] = f2bf(h);
        }
      }
    }
  }
}

// -------- GEMM2: 128x128 m97-style; out[t] += w*(H@Wo + bo), atomic --------------------------
// Dispatch: R8 order (dt inner over all 8, mt outer).
__global__ __launch_bounds__(256,4) void gemm2_k(const ushort_t* __restrict__ H,
    const ushort_t* __restrict__ WoT, const float* __restrict__ bo,
    const int* __restrict__ cnt, const int* __restrict__ offs,
    const int* __restrict__ elist, const float* __restrict__ wslot,
    float* __restrict__ out){
  __shared__ ushort_t As[128*64];
  __shared__ ushort_t Bs[128*64];
  int id = blockIdx.x;
  int e  = id & 7;                  // XCD pin
  int j_ = id >> 3;                 // 0..255
  int mt = j_ >> 3;                 // 0..31
  int dt = j_ & 7;                  // 0..7
  int cnte = cnt[e];
  if (mt*128 >= cnte) return;
  int row0 = offs[e] + mt*128;
  const ushort_t* Ag = H   + (size_t)row0*DFFC;
  const ushort_t* Bg = WoT + (size_t)e*DMODEL*DFFC + (size_t)(dt*128)*DFFC;
  int tid = threadIdx.x;
  int w = tid>>6, l = tid&63;
  int wr = w>>1, wc = w&1;

  int aOff[4][2], bOff[4][2];
  #pragma unroll
  for (int m=0;m<4;m++)
    #pragma unroll
    for (int ks=0;ks<2;ks++)
      aOff[m][ks] = frag_off(wr*64 + m*16 + (l&15), ks*4 + (l>>4));
  #pragma unroll
  for (int n=0;n<4;n++)
    #pragma unroll
    for (int ks=0;ks<2;ks++)
      bOff[n][ks] = frag_off(wc*64 + n*16 + (l&15), ks*4 + (l>>4));

  float4v acc[4][4];
  #pragma unroll
  for (int m=0;m<4;m++)
    #pragma unroll
    for (int n=0;n<4;n++) acc[m][n]=(float4v){0,0,0,0};

  const int KT = DFFC/64;     // 32
  for (int kt=0; kt<KT; ++kt){
    stage256(Ag + kt*64, DFFC, As, w, l);
    stage256(Bg + kt*64, DFFC, Bs, w, l);
    __syncthreads();
    #pragma unroll
    for (int ks=0; ks<2; ++ks){
      short8v a_[4], b_[4];
      #pragma unroll
      for (int m=0;m<4;m++) a_[m] = *(const short8v*)&As[aOff[m][ks]];
      #pragma unroll
      for (int n=0;n<4;n++) b_[n] = *(const short8v*)&Bs[bOff[n][ks]];
      #pragma unroll
      for (int n=0;n<4;n++)
        #pragma unroll
        for (int m=0;m<4;m++)
          acc[m][n] = __builtin_amdgcn_mfma_f32_16x16x32_bf16(a_[m], b_[n], acc[m][n], 0,0,0);
    }
    __syncthreads();
  }

  int rows_valid = cnte - mt*128; if (rows_valid>128) rows_valid=128;
  #pragma unroll
  for (int m=0;m<4;m++){
    #pragma unroll
    for (int r=0;r<4;r++){
      int row_local = wr*64 + m*16 + (l>>4)*4 + r;
      if (row_local < rows_valid){
        int li = mt*128 + row_local;
        int entry = elist[e*N_TOK + li];
        int tk = entry>>1;
        float wgt = wslot[entry];
        float* obase = out + (size_t)tk*DMODEL;
        #pragma unroll
        for (int n=0;n<4;n++){
          int d = dt*128 + wc*64 + n*16 + (l&15);
          atomicAdd(&obase[d], wgt * (acc[m][n][r] + bo[e*DMODEL + d]));
        }
      }
    }
  }
}

extern "C" void kernel_launch(void* const* d_in, const int* in_sizes, int n_in,
                              void* d_out, int out_size, void* d_ws, size_t ws_size,
                              hipStream_t stream){
  const float* x   = (const float*)d_in[0];
  const float* Wg  = (const float*)d_in[1];
  const float* bg  = (const float*)d_in[2];
  const float* Ww  = (const float*)d_in[3];
  const float* bwp = (const float*)d_in[4];
  const float* Wv  = (const float*)d_in[5];
  const float* bvp = (const float*)d_in[6];
  const float* Wo  = (const float*)d_in[7];
  const float* bop = (const float*)d_in[8];
  float* out = (float*)d_out;
  float* logits = out + (size_t)N_TOK*DMODEL;

  char* cur = (char*)d_ws;
  auto alloc = [&](size_t b)->char*{ char* p=cur; cur += (b+255)&~(size_t)255; return p; };
  int*      cnt     = (int*)     alloc(NEXP*4);
  int*      offs    = (int*)     alloc((NEXP+1)*4);
  int*      sel     = (int*)     alloc((size_t)N_TOK*4);
  float*    wslot   = (float*)   alloc((size_t)NR*4);
  int*      elist   = (int*)     alloc((size_t)NEXP*N_TOK*4);
  ushort_t* Xbf     = (ushort_t*)alloc((size_t)N_TOK*DMODEL*2);
  ushort_t* Hb      = (ushort_t*)alloc((size_t)NR*DFFC*2 + 256*DFFC*2);
  ushort_t* Bcat    = (ushort_t*)alloc((size_t)NEXP*2*DFFC*DMODEL*2);
  ushort_t* WoT     = (ushort_t*)alloc((size_t)NEXP*DMODEL*DFFC*2);
  (void)ws_size; (void)in_sizes; (void)n_in; (void)out_size;

  hipMemsetAsync(out, 0, (size_t)N_TOK*DMODEL*4, stream);   // gemm2 accumulates atomically
  router_k<<<N_TOK/4, 256, 0, stream>>>(x, Wg, bg, logits, sel, wslot, Xbf);
  build_k<<<NEXP, 256, 0, stream>>>(sel, elist, cnt);
  scan_k<<<1, 1, 0, stream>>>(cnt, offs);
  transpose_k<<<2048, 256, 0, stream>>>(Ww, Wv, Wo, Bcat, WoT);
  gemm1_k<<<NEXP*32*32, 256, 0, stream>>>(Xbf, elist, Bcat, bwp, bvp, cnt, offs, Hb);
  gemm2_k<<<NEXP*32*8, 256, 0, stream>>>(Hb, WoT, bop, cnt, offs, elist, wslot, out);
}

// Round 14
// 261.335 us; speedup vs baseline: 1.0375x; 1.0375x over previous
//
#include <hip/hip_runtime.h>
#include <cstdint>

#define N_TOK 4096
#define DMODEL 1024
#define DFFC 2048
#define NEXP 8
#define NR (N_TOK*2)      /* 8192 expanded rows (top-2) */

typedef unsigned short ushort_t;
typedef __attribute__((ext_vector_type(8))) short short8v;   // 8 bf16 / 16B
typedef __attribute__((ext_vector_type(4))) float float4v;   // MFMA C/D

__device__ __forceinline__ ushort_t f2bf(float f){
  union { float f; unsigned u; } v; v.f = f;
  unsigned r = v.u + 0x7fffu + ((v.u >> 16) & 1u);
  return (ushort_t)(r >> 16);
}

__device__ __forceinline__ float fcomp(const float4& v, int q){
  return q==0 ? v.x : q==1 ? v.y : q==2 ? v.z : v.w;
}

__device__ __forceinline__ void gl_lds16(const void* g, void* l){
  __builtin_amdgcn_global_load_lds((const __attribute__((address_space(1))) char*)g,
                                   (__attribute__((address_space(3))) char*)l, 16, 0, 0);
}

// swizzled fragment element-offset inside a [rows][64] bf16 tile (128B rows, 8 slots of 16B)
__device__ __forceinline__ int frag_off(int row, int slotc){
  return row*64 + ((slotc ^ (row & 7)))*8;
}

__device__ __forceinline__ void fma4(float4& a, float s, float4 q){
  a.x += s*q.x; a.y += s*q.y; a.z += s*q.z; a.w += s*q.w;
}

// ------- router (atomic-free): logits fp32 (exact), top-2 -> sel/wslot; emits bf16 x --------
// 256 thr = 4 waves, one token per wave.  [measured ~20 us]
__global__ __launch_bounds__(256) void router_k(const float* __restrict__ x,
                         const float* __restrict__ Wg, const float* __restrict__ bg,
                         float* __restrict__ logits, int* __restrict__ sel,
                         float* __restrict__ wslot, ushort_t* __restrict__ Xbf){
  int wid = threadIdx.x >> 6;
  int l   = threadIdx.x & 63;
  int t = blockIdx.x*4 + wid;
  const float4* xr = (const float4*)(x + (size_t)t * DMODEL);
  ushort_t* xb = Xbf + (size_t)t * DMODEL;
  float4 acc0 = {0,0,0,0}, acc1 = {0,0,0,0};
  #pragma unroll
  for (int it=0; it<4; ++it){
    int i4 = it*64 + l;
    float4 v = xr[i4];
    const float4* wr4 = (const float4*)(Wg + (size_t)i4*32);
    fma4(acc0, v.x, wr4[0]); fma4(acc1, v.x, wr4[1]);
    fma4(acc0, v.y, wr4[2]); fma4(acc1, v.y, wr4[3]);
    fma4(acc0, v.z, wr4[4]); fma4(acc1, v.z, wr4[5]);
    fma4(acc0, v.w, wr4[6]); fma4(acc1, v.w, wr4[7]);
    ushort4 o; o.x=f2bf(v.x); o.y=f2bf(v.y); o.z=f2bf(v.z); o.w=f2bf(v.w);
    *(ushort4*)(xb + 4*i4) = o;
  }
  float lg[NEXP] = {acc0.x, acc0.y, acc0.z, acc0.w, acc1.x, acc1.y, acc1.z, acc1.w};
  #pragma unroll
  for (int e=0;e<NEXP;e++){
    float v = lg[e];
    #pragma unroll
    for (int s=32;s>0;s>>=1) v += __shfl_xor(v,s);
    lg[e] = v;
  }
  if (l==0){
    float m=-1e30f;
    #pragma unroll
    for (int e=0;e<NEXP;e++){ lg[e]+=bg[e]; m = fmaxf(m,lg[e]); }
    float p[NEXP];
    #pragma unroll
    for (int e=0;e<NEXP;e++) p[e]=__expf(lg[e]-m);
    int e0=0;
    #pragma unroll
    for (int e=1;e<NEXP;e++) if (p[e]>p[e0]) e0=e;      // strict > : lower idx wins ties
    int e1=(e0==0)?1:0;
    #pragma unroll
    for (int e=0;e<NEXP;e++) if (e!=e0 && p[e]>p[e1]) e1=e;
    float ps=p[e0]+p[e1];
    float4* lgo = (float4*)(logits + (size_t)t*NEXP);
    lgo[0] = make_float4(lg[0],lg[1],lg[2],lg[3]);
    lgo[1] = make_float4(lg[4],lg[5],lg[6],lg[7]);
    sel[t] = e0 | (e1<<8);
    wslot[t*2+0]=p[e0]/ps; wslot[t*2+1]=p[e1]/ps;
  }
}

// ------- build_k: deterministic per-expert compaction, zero atomics (8 blocks) ---------------
__global__ __launch_bounds__(256) void build_k(const int* __restrict__ sel,
                                               int* __restrict__ elist, int* __restrict__ cnt){
  int e = blockIdx.x;
  int tid = threadIdx.x;
  int w = tid>>6, l = tid&63;
  __shared__ int wtot[4];
  __shared__ int runbase;
  if (tid==0) runbase = 0;
  __syncthreads();
  unsigned long long lt = (1ULL << l) - 1ULL;
  for (int c=0;c<N_TOK/256;c++){
    int t = c*256 + tid;
    int s = sel[t];
    bool f0 = (s & 255) == e;
    bool f1 = ((s>>8) & 255) == e;
    unsigned long long m0 = __ballot(f0);
    unsigned long long m1 = __ballot(f1);
    int myless = __popcll(m0 & lt) + __popcll(m1 & lt);
    if (l==0) wtot[w] = __popcll(m0) + __popcll(m1);
    __syncthreads();
    int pre = 0, tot = 0;
    #pragma unroll
    for (int j=0;j<4;j++){ if (j<w) pre += wtot[j]; tot += wtot[j]; }
    int base = runbase + pre + myless;
    if (f0) elist[e*N_TOK + base] = 2*t;
    if (f1) elist[e*N_TOK + base + (f0?1:0)] = 2*t + 1;
    __syncthreads();
    if (tid==0) runbase += tot;
    __syncthreads();
  }
  if (tid==0) cnt[e] = runbase;
}

__global__ void scan_k(const int* __restrict__ cnt, int* __restrict__ offs){
  if (threadIdx.x==0 && blockIdx.x==0){
    int s=0;
    for (int e=0;e<NEXP;e++){ offs[e]=s; s+=cnt[e]; }
    offs[NEXP]=s;
  }
}

// ------------- weight transpose + fp32->bf16, 8kx4f register blocks, 16B k-run stores --------
// 6144 blocks, e = id&7 XCD pin, one 128k x 64f tile per block, exact decode.
// Lane map: g=tid>>4 (k-oct), c=tid&15 (f-quad). Loads: 4x256B/inst. Stores: 16x64B full
// lines per inst (4 g-lanes x 16B contiguous per output row).
// Bcat[e] is [4096 cols][1024 k], col = (f>>4)*32 + (is_v?16:0) + (f&15).
__global__ __launch_bounds__(256) void transpose_k(const float* __restrict__ Ww,
                            const float* __restrict__ Wv, const float* __restrict__ Wo,
                            ushort_t* __restrict__ Bcat, ushort_t* __restrict__ WoT){
  int id = blockIdx.x;
  int e  = id & 7;                  // XCD pin: expert e -> XCD e
  int t8 = id >> 3;                 // 0..767
  const float* src; int F; int fx, kY; int m;
  if (t8 < 512){
    m = t8 >> 8;                    // 0=Ww 1=Wv
    int r = t8 & 255;
    src = (m ? Wv : Ww) + (size_t)e*DMODEL*DFFC;
    F = DFFC; fx = r & 31; kY = r >> 5;        // 32 f-tiles x 8 k-supertiles (K=1024)
  } else {
    m = 2;
    int r = t8 - 512;
    src = Wo + (size_t)e*DFFC*DMODEL;
    F = DMODEL; fx = r & 15; kY = r >> 4;      // 16 f-tiles x 16 k-supertiles (K=2048)
  }
  int tid = threadIdx.x;
  int g = tid >> 4;                 // k-oct 0..15
  int c = tid & 15;                 // f-quad 0..15 (consecutive lanes walk f: coalesced loads)
  int kk = kY*128 + 8*g;
  int ff = fx*64 + 4*c;
  float4 v[8];
  #pragma unroll
  for (int j=0;j<8;j++) v[j] = *(const float4*)&src[(size_t)(kk+j)*F + ff];
  short8v o[4];
  #pragma unroll
  for (int q=0;q<4;q++)
    #pragma unroll
    for (int j=0;j<8;j++)
      o[q][j] = (short)f2bf(fcomp(v[j], q));
  if (m < 2){
    #pragma unroll
    for (int q=0;q<4;q++){
      int f = ff + q;
      int cc = (f>>4)*32 + m*16 + (f&15);
      *(short8v*)&Bcat[((size_t)e*4096 + cc)*DMODEL + kk] = o[q];
    }
  } else {
    #pragma unroll
    for (int q=0;q<4;q++){
      int f = ff + q;
      *(short8v*)&WoT[(size_t)e*DMODEL*DFFC + (size_t)f*DFFC + kk] = o[q];
    }
  }
}

// ---- stage helper (256 thr): [128 rows][64 k] tile, 4 gl_lds/thread, inverse-swizzled src ---
__device__ __forceinline__ void stage256(const ushort_t* __restrict__ base, int ldk,
                                         ushort_t* buf, int w, int l){
  int sw = ((l&7) ^ (l>>3))*8;
  #pragma unroll
  for (int j=0;j<4;j++){
    int row = j*32 + w*8 + (l>>3);
    gl_lds16(base + (size_t)row*ldk + sw, &buf[(j*256 + w*64)*8]);
  }
}

// -------- GEMM1: 128x128 m97-style, A indirect via elist, B = interleaved Bcat ---------------
// 4 waves (2x2), single-buffered 32 KB LDS, 4 blocks/CU, expert e -> XCD e.
// Supertiled dispatch: j_ = fs*128 + mt*4 + ftSub  (ft groups of 4 inner, mt next, fs outer)
__global__ __launch_bounds__(256,4) void gemm1_k(const ushort_t* __restrict__ Xbf,
    const int* __restrict__ elist,
    const ushort_t* __restrict__ Bcat,
    const float* __restrict__ bw, const float* __restrict__ bv,
    const int* __restrict__ cnt, const int* __restrict__ offs,
    ushort_t* __restrict__ H){
  __shared__ ushort_t As[128*64];
  __shared__ ushort_t Bs[128*64];
  int id = blockIdx.x;
  int e  = id & 7;                  // XCD pin
  int j_ = id >> 3;                 // 0..1023
  int fs = j_ >> 7;                 // 0..7
  int mt = (j_ >> 2) & 31;          // 0..31
  int ft = fs*4 + (j_ & 3);         // 0..31
  int cnte = cnt[e];
  if (mt*128 >= cnte) return;
  int row0 = offs[e] + mt*128;
  const ushort_t* Bg = Bcat + ((size_t)e*4096 + ft*128)*DMODEL;
  int tid = threadIdx.x;
  int w = tid>>6, l = tid&63;
  int wr = w>>1, wc = w&1;          // wave: rows [wr*64,+64), cols [wc*64,+64)
  int sw = ((l&7) ^ (l>>3))*8;      // inverse-swizzled k-slot (A staging)

  // A indirection: token row per staged LDS row (clamped to valid range)
  int aTok[4];
  #pragma unroll
  for (int j=0;j<4;j++){
    int li = mt*128 + j*32 + w*8 + (l>>3);
    if (li >= cnte) li = cnte-1;
    aTok[j] = elist[e*N_TOK + li] >> 1;
  }

  int aOff[4][2], bOff[4][2];
  #pragma unroll
  for (int m=0;m<4;m++)
    #pragma unroll
    for (int ks=0;ks<2;ks++)
      aOff[m][ks] = frag_off(wr*64 + m*16 + (l&15), ks*4 + (l>>4));
  #pragma unroll
  for (int n=0;n<4;n++)
    #pragma unroll
    for (int ks=0;ks<2;ks++)
      bOff[n][ks] = frag_off(wc*64 + n*16 + (l&15), ks*4 + (l>>4));

  float4v acc[4][4];
  #pragma unroll
  for (int m=0;m<4;m++)
    #pragma unroll
    for (int n=0;n<4;n++) acc[m][n]=(float4v){0,0,0,0};

  const int KT = DMODEL/64;   // 16
  for (int kt=0; kt<KT; ++kt){
    #pragma unroll
    for (int j=0;j<4;j++)
      gl_lds16(Xbf + (size_t)aTok[j]*DMODEL + kt*64 + sw, &As[j*2048 + w*512]);
    stage256(Bg + kt*64, DMODEL, Bs, w, l);
    __syncthreads();
    #pragma unroll
    for (int ks=0; ks<2; ++ks){
      short8v a_[4], b_[4];
      #pragma unroll
      for (int m=0;m<4;m++) a_[m] = *(const short8v*)&As[aOff[m][ks]];
      #pragma unroll
      for (int n=0;n<4;n++) b_[n] = *(const short8v*)&Bs[bOff[n][ks]];
      #pragma unroll
      for (int n=0;n<4;n++)
        #pragma unroll
        for (int m=0;m<4;m++)
          acc[m][n] = __builtin_amdgcn_mfma_f32_16x16x32_bf16(a_[m], b_[n], acc[m][n], 0,0,0);
    }
    __syncthreads();
  }

  int rows_valid = cnte - mt*128; if (rows_valid>128) rows_valid=128;
  #pragma unroll
  for (int m=0;m<4;m++){
    #pragma unroll
    for (int r=0;r<4;r++){
      int row_local = wr*64 + m*16 + (l>>4)*4 + r;
      if (row_local < rows_valid){
        size_t hbase = (size_t)(row0 + row_local)*DFFC;
        #pragma unroll
        for (int np=0;np<2;np++){
          int f = ft*64 + wc*32 + np*16 + (l&15);
          float wx = acc[m][2*np+0][r] + bw[e*DFFC + f];
          float vx = acc[m][2*np+1][r] + bv[e*DFFC + f];
          float h = (wx / (1.f + __expf(-wx))) * vx;
          H[hbase + f] = f2bf(h);
        }
      }
    }
  }
}

// -------- GEMM2: 128x128 m97-style; out[t] += w*(H@Wo + bo), atomic --------------------------
// Dispatch: R8 order (dt inner over all 8, mt outer).
__global__ __launch_bounds__(256,4) void gemm2_k(const ushort_t* __restrict__ H,
    const ushort_t* __restrict__ WoT, const float* __restrict__ bo,
    const int* __restrict__ cnt, const int* __restrict__ offs,
    const int* __restrict__ elist, const float* __restrict__ wslot,
    float* __restrict__ out){
  __shared__ ushort_t As[128*64];
  __shared__ ushort_t Bs[128*64];
  int id = blockIdx.x;
  int e  = id & 7;                  // XCD pin
  int j_ = id >> 3;                 // 0..255
  int mt = j_ >> 3;                 // 0..31
  int dt = j_ & 7;                  // 0..7
  int cnte = cnt[e];
  if (mt*128 >= cnte) return;
  int row0 = offs[e] + mt*128;
  const ushort_t* Ag = H   + (size_t)row0*DFFC;
  const ushort_t* Bg = WoT + (size_t)e*DMODEL*DFFC + (size_t)(dt*128)*DFFC;
  int tid = threadIdx.x;
  int w = tid>>6, l = tid&63;
  int wr = w>>1, wc = w&1;

  int aOff[4][2], bOff[4][2];
  #pragma unroll
  for (int m=0;m<4;m++)
    #pragma unroll
    for (int ks=0;ks<2;ks++)
      aOff[m][ks] = frag_off(wr*64 + m*16 + (l&15), ks*4 + (l>>4));
  #pragma unroll
  for (int n=0;n<4;n++)
    #pragma unroll
    for (int ks=0;ks<2;ks++)
      bOff[n][ks] = frag_off(wc*64 + n*16 + (l&15), ks*4 + (l>>4));

  float4v acc[4][4];
  #pragma unroll
  for (int m=0;m<4;m++)
    #pragma unroll
    for (int n=0;n<4;n++) acc[m][n]=(float4v){0,0,0,0};

  const int KT = DFFC/64;     // 32
  for (int kt=0; kt<KT; ++kt){
    stage256(Ag + kt*64, DFFC, As, w, l);
    stage256(Bg + kt*64, DFFC, Bs, w, l);
    __syncthreads();
    #pragma unroll
    for (int ks=0; ks<2; ++ks){
      short8v a_[4], b_[4];
      #pragma unroll
      for (int m=0;m<4;m++) a_[m] = *(const short8v*)&As[aOff[m][ks]];
      #pragma unroll
      for (int n=0;n<4;n++) b_[n] = *(const short8v*)&Bs[bOff[n][ks]];
      #pragma unroll
      for (int n=0;n<4;n++)
        #pragma unroll
        for (int m=0;m<4;m++)
          acc[m][n] = __builtin_amdgcn_mfma_f32_16x16x32_bf16(a_[m], b_[n], acc[m][n], 0,0,0);
    }
    __syncthreads();
  }

  int rows_valid = cnte - mt*128; if (rows_valid>128) rows_valid=128;
  #pragma unroll
  for (int m=0;m<4;m++){
    #pragma unroll
    for (int r=0;r<4;r++){
      int row_local = wr*64 + m*16 + (l>>4)*4 + r;
      if (row_local < rows_valid){
        int li = mt*128 + row_local;
        int entry = elist[e*N_TOK + li];
        int tk = entry>>1;
        float wgt = wslot[entry];
        float* obase = out + (size_t)tk*DMODEL;
        #pragma unroll
        for (int n=0;n<4;n++){
          int d = dt*128 + wc*64 + n*16 + (l&15);
          atomicAdd(&obase[d], wgt * (acc[m][n][r] + bo[e*DMODEL + d]));
        }
      }
    }
  }
}

extern "C" void kernel_launch(void* const* d_in, const int* in_sizes, int n_in,
                              void* d_out, int out_size, void* d_ws, size_t ws_size,
                              hipStream_t stream){
  const float* x   = (const float*)d_in[0];
  const float* Wg  = (const float*)d_in[1];
  const float* bg  = (const float*)d_in[2];
  const float* Ww  = (const float*)d_in[3];
  const float* bwp = (const float*)d_in[4];
  const float* Wv  = (const float*)d_in[5];
  const float* bvp = (const float*)d_in[6];
  const float* Wo  = (const float*)d_in[7];
  const float* bop = (const float*)d_in[8];
  float* out = (float*)d_out;
  float* logits = out + (size_t)N_TOK*DMODEL;

  char* cur = (char*)d_ws;
  auto alloc = [&](size_t b)->char*{ char* p=cur; cur += (b+255)&~(size_t)255; return p; };
  int*      cnt     = (int*)     alloc(NEXP*4);
  int*      offs    = (int*)     alloc((NEXP+1)*4);
  int*      sel     = (int*)     alloc((size_t)N_TOK*4);
  float*    wslot   = (float*)   alloc((size_t)NR*4);
  int*      elist   = (int*)     alloc((size_t)NEXP*N_TOK*4);
  ushort_t* Xbf     = (ushort_t*)alloc((size_t)N_TOK*DMODEL*2);
  ushort_t* Hb      = (ushort_t*)alloc((size_t)NR*DFFC*2 + 256*DFFC*2);
  ushort_t* Bcat    = (ushort_t*)alloc((size_t)NEXP*2*DFFC*DMODEL*2);
  ushort_t* WoT     = (ushort_t*)alloc((size_t)NEXP*DMODEL*DFFC*2);
  (void)ws_size; (void)in_sizes; (void)n_in; (void)out_size;

  hipMemsetAsync(out, 0, (size_t)N_TOK*DMODEL*4, stream);   // gemm2 accumulates atomically
  router_k<<<N_TOK/4, 256, 0, stream>>>(x, Wg, bg, logits, sel, wslot, Xbf);
  build_k<<<NEXP, 256, 0, stream>>>(sel, elist, cnt);
  scan_k<<<1, 1, 0, stream>>>(cnt, offs);
  transpose_k<<<6144, 256, 0, stream>>>(Ww, Wv, Wo, Bcat, WoT);
  gemm1_k<<<NEXP*32*32, 256, 0, stream>>>(Xbf, elist, Bcat, bwp, bvp, cnt, offs, Hb);
  gemm2_k<<<NEXP*32*8, 256, 0, stream>>>(Hb, WoT, bop, cnt, offs, elist, wslot, out);
}